// Round 1
// baseline (79.699 us; speedup 1.0000x reference)
//
#include <hip/hip_runtime.h>

// Octonion multiply: out = a * b, rows of 8 fp32 (1 real + 7 imaginary).
// Memory-bound elementwise: 96 B traffic / 120 FLOP per row.

__global__ void __launch_bounds__(256)
octo_mul_kernel(const float4* __restrict__ a4,
                const float4* __restrict__ b4,
                float4* __restrict__ o4,
                int n)
{
    int idx = blockIdx.x * blockDim.x + threadIdx.x;
    int stride = gridDim.x * blockDim.x;
    for (int i = idx; i < n; i += stride) {
        float4 al = a4[2 * i];
        float4 ah = a4[2 * i + 1];
        float4 bl = b4[2 * i];
        float4 bh = b4[2 * i + 1];

        float a0 = al.x;
        float x0 = al.y, x1 = al.z, x2 = al.w;
        float x3 = ah.x, x4 = ah.y, x5 = ah.z, x6 = ah.w;
        float b0 = bl.x;
        float y0 = bl.y, y1 = bl.z, y2 = bl.w;
        float y3 = bh.x, y4 = bh.y, y5 = bh.z, y6 = bh.w;

        // real = a0*b0 - <a_im, b_im>
        float real = a0 * b0
                   - (x0 * y0 + x1 * y1 + x2 * y2 + x3 * y3
                    + x4 * y4 + x5 * y5 + x6 * y6);

        // Cross terms from Fano triples (0,1,2)(0,3,4)(0,6,5)(1,3,5)(1,4,6)(2,3,6)(2,5,4):
        // per triple (i,j,k): c[k]+=x_i y_j - x_j y_i ; c[i]+=x_j y_k - x_k y_j ; c[j]+=x_k y_i - x_i y_k
        float c0 = x1 * y2 - x2 * y1 + x3 * y4 - x4 * y3 + x6 * y5 - x5 * y6;
        float c1 = x2 * y0 - x0 * y2 + x3 * y5 - x5 * y3 + x4 * y6 - x6 * y4;
        float c2 = x0 * y1 - x1 * y0 + x3 * y6 - x6 * y3 + x5 * y4 - x4 * y5;
        float c3 = x4 * y0 - x0 * y4 + x5 * y1 - x1 * y5 + x6 * y2 - x2 * y6;
        float c4 = x0 * y3 - x3 * y0 + x6 * y1 - x1 * y6 + x2 * y5 - x5 * y2;
        float c5 = x0 * y6 - x6 * y0 + x1 * y3 - x3 * y1 + x4 * y2 - x2 * y4;
        float c6 = x5 * y0 - x0 * y5 + x1 * y4 - x4 * y1 + x2 * y3 - x3 * y2;

        float4 ol, oh;
        ol.x = real;
        ol.y = a0 * y0 + b0 * x0 + c0;
        ol.z = a0 * y1 + b0 * x1 + c1;
        ol.w = a0 * y2 + b0 * x2 + c2;
        oh.x = a0 * y3 + b0 * x3 + c3;
        oh.y = a0 * y4 + b0 * x4 + c4;
        oh.z = a0 * y5 + b0 * x5 + c5;
        oh.w = a0 * y6 + b0 * x6 + c6;

        o4[2 * i]     = ol;
        o4[2 * i + 1] = oh;
    }
}

extern "C" void kernel_launch(void* const* d_in, const int* in_sizes, int n_in,
                              void* d_out, int out_size, void* d_ws, size_t ws_size,
                              hipStream_t stream) {
    const float4* a4 = (const float4*)d_in[0];
    const float4* b4 = (const float4*)d_in[1];
    float4* o4 = (float4*)d_out;
    int n = in_sizes[0] / 8;  // octonion count

    const int block = 256;
    int grid = (n + block - 1) / block;
    if (grid > 2048) grid = 2048;  // grid-stride the rest (G11)
    octo_mul_kernel<<<grid, block, 0, stream>>>(a4, b4, o4, n);
}

// Round 3
// 75.272 us; speedup vs baseline: 1.0588x; 1.0588x over previous
//
#include <hip/hip_runtime.h>

// Octonion multiply, fully-coalesced version (R3).
// Every global load/store instruction is lane-contiguous (lane i <-> float4 base+i).
// Halves are redistributed between even/odd lane pairs via __shfl_xor(.,1)
// (lane 2k <-> 2k+1). R2's update_dpp exchange produced masked/zeroed lanes;
// __shfl_xor has HIP-guaranteed semantics.
// Even thread t computes octonion tileO + t/2; odd thread computes tileO + 128 + t/2.

typedef float f32x4 __attribute__((ext_vector_type(4)));

__device__ __forceinline__ f32x4 xor1_swap(f32x4 v) {
    f32x4 r;
#pragma unroll
    for (int c = 0; c < 4; ++c)
        r[c] = __shfl_xor(v[c], 1, 64);
    return r;
}

__device__ __forceinline__ void octo_compute(f32x4 al, f32x4 ah, f32x4 bl, f32x4 bh,
                                             f32x4& ol, f32x4& oh) {
    float a0 = al[0];
    float x0 = al[1], x1 = al[2], x2 = al[3];
    float x3 = ah[0], x4 = ah[1], x5 = ah[2], x6 = ah[3];
    float b0 = bl[0];
    float y0 = bl[1], y1 = bl[2], y2 = bl[3];
    float y3 = bh[0], y4 = bh[1], y5 = bh[2], y6 = bh[3];

    float real = a0 * b0
               - (x0 * y0 + x1 * y1 + x2 * y2 + x3 * y3
                + x4 * y4 + x5 * y5 + x6 * y6);

    // Fano triples (0,1,2)(0,3,4)(0,6,5)(1,3,5)(1,4,6)(2,3,6)(2,5,4)
    float c0 = x1 * y2 - x2 * y1 + x3 * y4 - x4 * y3 + x6 * y5 - x5 * y6;
    float c1 = x2 * y0 - x0 * y2 + x3 * y5 - x5 * y3 + x4 * y6 - x6 * y4;
    float c2 = x0 * y1 - x1 * y0 + x3 * y6 - x6 * y3 + x5 * y4 - x4 * y5;
    float c3 = x4 * y0 - x0 * y4 + x5 * y1 - x1 * y5 + x6 * y2 - x2 * y6;
    float c4 = x0 * y3 - x3 * y0 + x6 * y1 - x1 * y6 + x2 * y5 - x5 * y2;
    float c5 = x0 * y6 - x6 * y0 + x1 * y3 - x3 * y1 + x4 * y2 - x2 * y4;
    float c6 = x5 * y0 - x0 * y5 + x1 * y4 - x4 * y1 + x2 * y3 - x3 * y2;

    ol[0] = real;
    ol[1] = a0 * y0 + b0 * x0 + c0;
    ol[2] = a0 * y1 + b0 * x1 + c1;
    ol[3] = a0 * y2 + b0 * x2 + c2;
    oh[0] = a0 * y3 + b0 * x3 + c3;
    oh[1] = a0 * y4 + b0 * x4 + c4;
    oh[2] = a0 * y5 + b0 * x5 + c5;
    oh[3] = a0 * y6 + b0 * x6 + c6;
}

__global__ void __launch_bounds__(256)
octo_mul_coal(const f32x4* __restrict__ a4,
              const f32x4* __restrict__ b4,
              f32x4* __restrict__ o4,
              int n)  // n = octonion count
{
    const int t = threadIdx.x;
    const int tileO = blockIdx.x * 256;  // octonion tile base
    const int fb = tileO * 2;            // float4 tile base

    if (tileO + 256 <= n) {
        // ---- fast path: fully-coalesced tile ----
        // float4 #(fb+t)      -> oct tileO + t/2,        half t&1
        // float4 #(fb+t+256)  -> oct tileO + 128 + t/2,  half t&1
        f32x4 ar0 = a4[fb + t];
        f32x4 ar1 = a4[fb + t + 256];
        f32x4 br0 = b4[fb + t];
        f32x4 br1 = b4[fb + t + 256];

        const bool odd = (t & 1);

        // exchange: even lane needs odd neighbor's r0 (its oct's half1);
        //           odd lane needs even neighbor's r1 (its oct's half0)
        f32x4 asend = odd ? ar0 : ar1;
        f32x4 arecv = xor1_swap(asend);
        f32x4 a_h0 = odd ? arecv : ar0;
        f32x4 a_h1 = odd ? ar1 : arecv;

        f32x4 bsend = odd ? br0 : br1;
        f32x4 brecv = xor1_swap(bsend);
        f32x4 b_h0 = odd ? brecv : br0;
        f32x4 b_h1 = odd ? br1 : brecv;

        f32x4 o_h0, o_h1;
        octo_compute(a_h0, a_h1, b_h0, b_h1, o_h0, o_h1);

        // output exchange: slot fb+t needs (even: own h0, odd: even's h1)
        //                  slot fb+t+256 needs (even: odd's h0, odd: own h1)
        f32x4 osend = odd ? o_h0 : o_h1;
        f32x4 orecv = xor1_swap(osend);
        f32x4 s_lo = odd ? orecv : o_h0;
        f32x4 s_hi = odd ? o_h1 : orecv;

        // nontemporal: keep the output stream from evicting inputs out of L3
        __builtin_nontemporal_store(s_lo, &o4[fb + t]);
        __builtin_nontemporal_store(s_hi, &o4[fb + t + 256]);
    } else {
        // ---- tail path: per-thread strided (correctness only) ----
        int i = tileO + t;
        if (i < n) {
            f32x4 al = a4[2 * i], ah = a4[2 * i + 1];
            f32x4 bl = b4[2 * i], bh = b4[2 * i + 1];
            f32x4 ol, oh;
            octo_compute(al, ah, bl, bh, ol, oh);
            o4[2 * i]     = ol;
            o4[2 * i + 1] = oh;
        }
    }
}

extern "C" void kernel_launch(void* const* d_in, const int* in_sizes, int n_in,
                              void* d_out, int out_size, void* d_ws, size_t ws_size,
                              hipStream_t stream) {
    const f32x4* a4 = (const f32x4*)d_in[0];
    const f32x4* b4 = (const f32x4*)d_in[1];
    f32x4* o4 = (f32x4*)d_out;
    int n = in_sizes[0] / 8;  // octonion count

    const int block = 256;
    int grid = (n + block - 1) / block;  // full grid, one octonion per thread
    octo_mul_coal<<<grid, block, 0, stream>>>(a4, b4, o4, n);
}

// Round 4
// 62.577 us; speedup vs baseline: 1.2736x; 1.2029x over previous
//
#include <hip/hip_runtime.h>

// Octonion multiply R4: coalesced + persistent blocks + 2-stage software pipeline.
// - Lane-contiguous float4 loads/stores (R3 pattern), halves exchanged between
//   even/odd lane pairs via __shfl_xor(.,1).
// - 2048 persistent blocks, each walks 8 tiles; next tile's 4 loads are issued
//   BEFORE current tile's compute+store (8 loads in flight per wave).
// - Nontemporal stores keep the output stream from evicting inputs out of L3.

typedef float f32x4 __attribute__((ext_vector_type(4)));

__device__ __forceinline__ f32x4 xor1_swap(f32x4 v) {
    f32x4 r;
#pragma unroll
    for (int c = 0; c < 4; ++c)
        r[c] = __shfl_xor(v[c], 1, 64);
    return r;
}

__device__ __forceinline__ void octo_compute(f32x4 al, f32x4 ah, f32x4 bl, f32x4 bh,
                                             f32x4& ol, f32x4& oh) {
    float a0 = al[0];
    float x0 = al[1], x1 = al[2], x2 = al[3];
    float x3 = ah[0], x4 = ah[1], x5 = ah[2], x6 = ah[3];
    float b0 = bl[0];
    float y0 = bl[1], y1 = bl[2], y2 = bl[3];
    float y3 = bh[0], y4 = bh[1], y5 = bh[2], y6 = bh[3];

    float real = a0 * b0
               - (x0 * y0 + x1 * y1 + x2 * y2 + x3 * y3
                + x4 * y4 + x5 * y5 + x6 * y6);

    // Fano triples (0,1,2)(0,3,4)(0,6,5)(1,3,5)(1,4,6)(2,3,6)(2,5,4)
    float c0 = x1 * y2 - x2 * y1 + x3 * y4 - x4 * y3 + x6 * y5 - x5 * y6;
    float c1 = x2 * y0 - x0 * y2 + x3 * y5 - x5 * y3 + x4 * y6 - x6 * y4;
    float c2 = x0 * y1 - x1 * y0 + x3 * y6 - x6 * y3 + x5 * y4 - x4 * y5;
    float c3 = x4 * y0 - x0 * y4 + x5 * y1 - x1 * y5 + x6 * y2 - x2 * y6;
    float c4 = x0 * y3 - x3 * y0 + x6 * y1 - x1 * y6 + x2 * y5 - x5 * y2;
    float c5 = x0 * y6 - x6 * y0 + x1 * y3 - x3 * y1 + x4 * y2 - x2 * y4;
    float c6 = x5 * y0 - x0 * y5 + x1 * y4 - x4 * y1 + x2 * y3 - x3 * y2;

    ol[0] = real;
    ol[1] = a0 * y0 + b0 * x0 + c0;
    ol[2] = a0 * y1 + b0 * x1 + c1;
    ol[3] = a0 * y2 + b0 * x2 + c2;
    oh[0] = a0 * y3 + b0 * x3 + c3;
    oh[1] = a0 * y4 + b0 * x4 + c4;
    oh[2] = a0 * y5 + b0 * x5 + c5;
    oh[3] = a0 * y6 + b0 * x6 + c6;
}

__device__ __forceinline__ void exchange_compute_store(
    f32x4 ar0, f32x4 ar1, f32x4 br0, f32x4 br1,
    f32x4* __restrict__ o4, int fb, int t, bool odd)
{
    // exchange: even lane needs odd neighbor's r0 (its oct's half1);
    //           odd lane needs even neighbor's r1 (its oct's half0)
    f32x4 asend = odd ? ar0 : ar1;
    f32x4 arecv = xor1_swap(asend);
    f32x4 a_h0 = odd ? arecv : ar0;
    f32x4 a_h1 = odd ? ar1 : arecv;

    f32x4 bsend = odd ? br0 : br1;
    f32x4 brecv = xor1_swap(bsend);
    f32x4 b_h0 = odd ? brecv : br0;
    f32x4 b_h1 = odd ? br1 : brecv;

    f32x4 o_h0, o_h1;
    octo_compute(a_h0, a_h1, b_h0, b_h1, o_h0, o_h1);

    f32x4 osend = odd ? o_h0 : o_h1;
    f32x4 orecv = xor1_swap(osend);
    f32x4 s_lo = odd ? orecv : o_h0;
    f32x4 s_hi = odd ? o_h1 : orecv;

    __builtin_nontemporal_store(s_lo, &o4[fb + t]);
    __builtin_nontemporal_store(s_hi, &o4[fb + t + 256]);
}

__global__ void __launch_bounds__(256)
octo_mul_pipe(const f32x4* __restrict__ a4,
              const f32x4* __restrict__ b4,
              f32x4* __restrict__ o4,
              int n)  // n = octonion count
{
    const int t = threadIdx.x;
    const bool odd = (t & 1);
    const int nTiles = n >> 8;          // full 256-octonion tiles
    const int stride = gridDim.x;

    int tile = blockIdx.x;
    if (tile < nTiles) {
        int fb = tile * 512;
        f32x4 ar0 = a4[fb + t];
        f32x4 ar1 = a4[fb + t + 256];
        f32x4 br0 = b4[fb + t];
        f32x4 br1 = b4[fb + t + 256];

        for (;;) {
            int next = tile + stride;
            bool have_next = next < nTiles;
            f32x4 nar0, nar1, nbr0, nbr1;
            if (have_next) {
                int nfb = next * 512;
                nar0 = a4[nfb + t];
                nar1 = a4[nfb + t + 256];
                nbr0 = b4[nfb + t];
                nbr1 = b4[nfb + t + 256];
            }

            exchange_compute_store(ar0, ar1, br0, br1, o4, fb, t, odd);

            if (!have_next) break;
            tile = next;
            fb = next * 512;
            ar0 = nar0; ar1 = nar1; br0 = nbr0; br1 = nbr1;
        }
    }

    // tail (n not multiple of 256): covered by block 0, scalar path
    if (blockIdx.x == 0) {
        int i = nTiles * 256 + t;
        if (i < n) {
            f32x4 al = a4[2 * i], ah = a4[2 * i + 1];
            f32x4 bl = b4[2 * i], bh = b4[2 * i + 1];
            f32x4 ol, oh;
            octo_compute(al, ah, bl, bh, ol, oh);
            o4[2 * i]     = ol;
            o4[2 * i + 1] = oh;
        }
    }
}

extern "C" void kernel_launch(void* const* d_in, const int* in_sizes, int n_in,
                              void* d_out, int out_size, void* d_ws, size_t ws_size,
                              hipStream_t stream) {
    const f32x4* a4 = (const f32x4*)d_in[0];
    const f32x4* b4 = (const f32x4*)d_in[1];
    f32x4* o4 = (f32x4*)d_out;
    int n = in_sizes[0] / 8;  // octonion count

    const int block = 256;
    int nTiles = n / block;
    int grid = nTiles < 2048 ? (nTiles > 0 ? nTiles : 1) : 2048;  // persistent blocks
    octo_mul_pipe<<<grid, block, 0, stream>>>(a4, b4, o4, n);
}